// Round 6
// baseline (153.492 us; speedup 1.0000x reference)
//
#include <hip/hip_runtime.h>
#include <hip/hip_bf16.h>
#include <math.h>

// Problem constants (from reference setup_inputs)
constexpr int B_  = 8;
constexpr int CIN = 3;
constexpr int C_  = 64;
constexpr int H_  = 256;
constexpr int W_  = 256;
constexpr int TAPS = 9;   // K*K, K=3

typedef float f32x4 __attribute__((ext_vector_type(4)));

// ============================================================================
// Kernel 1 (compute-bound): kern[b][y][t][x] = conv1x1(relu(conv3x3(lr)))
// One block per (b,y) row, thread = x pixel. ~2.4K FMA/thread, tiny memory.
// ============================================================================
__global__ __launch_bounds__(256, 4)
void hsa_kern(const float* __restrict__ lr,
              const float* __restrict__ w1,
              const float* __restrict__ b1,
              const float* __restrict__ w2,
              const float* __restrict__ b2,
              float* __restrict__ kws)
{
    __shared__ float w2t[C_][12];       // transposed 1x1 weights

    const int tid = threadIdx.x;
    const int blk = blockIdx.x;         // 0 .. B_*H_-1
    const int b = blk / H_;
    const int y = blk % H_;

    for (int i = tid; i < TAPS * C_; i += 256) {
        const int t = i / C_;
        const int c = i % C_;
        w2t[c][t] = w2[i];
    }
    __syncthreads();

    const int x = tid;                  // 0..255
    float win[CIN][3][3];
    #pragma unroll
    for (int ci = 0; ci < CIN; ++ci) {
        #pragma unroll
        for (int r = 0; r < 3; ++r) {
            const int yy = y + r - 1;
            const bool vy = (unsigned)yy < (unsigned)H_;
            const float* row = lr + ((size_t)(b * CIN + ci) * H_ + yy) * W_;
            win[ci][r][0] = (vy && x > 0)       ? row[x - 1] : 0.f;
            win[ci][r][1] = vy                   ? row[x]     : 0.f;
            win[ci][r][2] = (vy && x < W_ - 1)  ? row[x + 1] : 0.f;
        }
    }

    float acc[TAPS];
    #pragma unroll
    for (int t = 0; t < TAPS; ++t) acc[t] = b2[t];

    for (int c = 0; c < C_; ++c) {
        // conv1 (3x3, cin=3): three 9-deep chains (wave-uniform weights)
        const float* wc = w1 + c * 27;
        float h0 = b1[c], h1 = 0.f, h2 = 0.f;
        #pragma unroll
        for (int r = 0; r < 3; ++r)
            #pragma unroll
            for (int j = 0; j < 3; ++j) {
                h0 = fmaf(wc[(0 * 3 + r) * 3 + j], win[0][r][j], h0);
                h1 = fmaf(wc[(1 * 3 + r) * 3 + j], win[1][r][j], h1);
                h2 = fmaf(wc[(2 * 3 + r) * 3 + j], win[2][r][j], h2);
            }
        const float hsum = fmaxf((h0 + h1) + h2, 0.f);   // ReLU

        const float4 wa = *(const float4*)&w2t[c][0];
        const float4 wb = *(const float4*)&w2t[c][4];
        const float  w8 = w2t[c][8];
        acc[0] = fmaf(wa.x, hsum, acc[0]);
        acc[1] = fmaf(wa.y, hsum, acc[1]);
        acc[2] = fmaf(wa.z, hsum, acc[2]);
        acc[3] = fmaf(wa.w, hsum, acc[3]);
        acc[4] = fmaf(wb.x, hsum, acc[4]);
        acc[5] = fmaf(wb.y, hsum, acc[5]);
        acc[6] = fmaf(wb.z, hsum, acc[6]);
        acc[7] = fmaf(wb.w, hsum, acc[7]);
        acc[8] = fmaf(w8,  hsum, acc[8]);
    }

    // kws layout [b][y][t][x] -> 9 coalesced 1KB stores
    float* kr = kws + (size_t)(b * H_ + y) * TAPS * W_;
    #pragma unroll
    for (int t = 0; t < TAPS; ++t) kr[t * W_ + x] = acc[t];
}

// ============================================================================
// Kernel 2 (memory-bound, streaming): out = h * sigmoid(sum shifted(h)*kern)
// NO LDS, NO barrier. One wave = one (batch, channel-pair, row): loads its 9
// kern taps + 6 h row-vectors back-to-back (15 loads in flight at wave start),
// computes both channels via cross-lane shuffles, stores 2 rows. 65K short
// independent waves -> continuous issue / deep MLP.
// XCD swizzle: 16384 blocks = 8 XCDs x 2048; each XCD owns one batch b, so
// that batch's kern rows (2.4 MB) stay resident in its private L2 across all
// 32 channel-pair sweeps; h halo reuse comes from adjacent-virt blocks.
// ============================================================================
__global__ __launch_bounds__(256, 4)
void hsa_gate(const float* __restrict__ hin,
              const float* __restrict__ kws,
              float* __restrict__ out)
{
    const int tid  = threadIdx.x;
    const int lane = tid & 63;
    const int wv   = tid >> 6;            // 0..3
    const int bid  = blockIdx.x;
    const int virt = (bid & 7) * 2048 + (bid >> 3);   // bijective, 16384=8*2048
    const int b    = virt >> 11;          // batch (one per XCD)
    const int cp   = (virt >> 6) & 31;    // channel pair
    const int yb   = virt & 63;           // row band
    const int y    = yb * 4 + wv;         // this wave's row
    const int x0   = lane * 4;

    // ---- batched loads: 9 kern taps + 2x3 h rows, all issued before use ----
    const float* kr = kws + (size_t)(b * H_ + y) * TAPS * W_ + x0;
    float4 kt[TAPS];
    #pragma unroll
    for (int t = 0; t < TAPS; ++t) kt[t] = *(const float4*)(kr + t * W_);

    const int c0 = cp * 2;
    const float* hb0 = hin + (size_t)(b * C_ + c0) * H_ * W_;
    const float* hb1 = hb0 + (size_t)H_ * W_;
    const bool vy0 = (y > 0);
    const bool vy2 = (y < H_ - 1);
    const float4 z4 = make_float4(0.f, 0.f, 0.f, 0.f);

    float4 m0[3], m1[3];
    m0[0] = vy0 ? *(const float4*)(hb0 + (size_t)(y - 1) * W_ + x0) : z4;
    m0[1] =       *(const float4*)(hb0 + (size_t)(y    ) * W_ + x0);
    m0[2] = vy2 ? *(const float4*)(hb0 + (size_t)(y + 1) * W_ + x0) : z4;
    m1[0] = vy0 ? *(const float4*)(hb1 + (size_t)(y - 1) * W_ + x0) : z4;
    m1[1] =       *(const float4*)(hb1 + (size_t)(y    ) * W_ + x0);
    m1[2] = vy2 ? *(const float4*)(hb1 + (size_t)(y + 1) * W_ + x0) : z4;

    // ---- per-channel compute ----
    #pragma unroll
    for (int q = 0; q < 2; ++q) {
        const float4* m = (q == 0) ? m0 : m1;

        float sim0 = 0.f, sim1 = 0.f, sim2 = 0.f, sim3 = 0.f;
        #pragma unroll
        for (int r = 0; r < 3; ++r) {
            const float4 mv = m[r];
            // column halo via cross-lane shuffle (wave spans the full row)
            float l  = __shfl_up(mv.w, 1);
            float rr = __shfl_down(mv.x, 1);
            if (lane == 0)  l  = 0.f;     // x = -1 zero pad
            if (lane == 63) rr = 0.f;     // x = 256 zero pad

            const float w6_0 = l;
            const float w6_1 = mv.x;
            const float w6_2 = mv.y;
            const float w6_3 = mv.z;
            const float w6_4 = mv.w;
            const float w6_5 = rr;
            {
                const float4 k4 = kt[r * 3 + 0];   // j = 0
                sim0 = fmaf(w6_0, k4.x, sim0);
                sim1 = fmaf(w6_1, k4.y, sim1);
                sim2 = fmaf(w6_2, k4.z, sim2);
                sim3 = fmaf(w6_3, k4.w, sim3);
            }
            {
                const float4 k4 = kt[r * 3 + 1];   // j = 1
                sim0 = fmaf(w6_1, k4.x, sim0);
                sim1 = fmaf(w6_2, k4.y, sim1);
                sim2 = fmaf(w6_3, k4.z, sim2);
                sim3 = fmaf(w6_4, k4.w, sim3);
            }
            {
                const float4 k4 = kt[r * 3 + 2];   // j = 2
                sim0 = fmaf(w6_2, k4.x, sim0);
                sim1 = fmaf(w6_3, k4.y, sim1);
                sim2 = fmaf(w6_4, k4.z, sim2);
                sim3 = fmaf(w6_5, k4.w, sim3);
            }
        }

        float4 o;
        o.x = m[1].x * __builtin_amdgcn_rcpf(1.f + __expf(-sim0));
        o.y = m[1].y * __builtin_amdgcn_rcpf(1.f + __expf(-sim1));
        o.z = m[1].z * __builtin_amdgcn_rcpf(1.f + __expf(-sim2));
        o.w = m[1].w * __builtin_amdgcn_rcpf(1.f + __expf(-sim3));
        *(float4*)(out + ((size_t)(b * C_ + c0 + q) * H_ + y) * W_ + x0) = o;
    }
}

// ============================================================================
// Fallback: single fused kernel (used only if ws_size is too small)
// ============================================================================
__global__ __launch_bounds__(256, 4)
void hsa_fused(const float* __restrict__ lr,
               const float* __restrict__ hin,
               const float* __restrict__ w1,
               const float* __restrict__ b1,
               const float* __restrict__ w2,
               const float* __restrict__ b2,
               float* __restrict__ out)
{
    __shared__ float kernS[TAPS][W_];
    __shared__ float w2t[C_][12];

    const int tid = threadIdx.x;
    const int blk = blockIdx.x;
    const int b = blk / H_;
    const int y = blk % H_;

    for (int i = tid; i < TAPS * C_; i += 256) {
        const int t = i / C_;
        const int c = i % C_;
        w2t[c][t] = w2[i];
    }
    __syncthreads();

    {
        const int x = tid;
        float win[CIN][3][3];
        #pragma unroll
        for (int ci = 0; ci < CIN; ++ci)
            #pragma unroll
            for (int r = 0; r < 3; ++r) {
                const int yy = y + r - 1;
                const bool vy = (unsigned)yy < (unsigned)H_;
                const float* row = lr + ((size_t)(b * CIN + ci) * H_ + yy) * W_;
                win[ci][r][0] = (vy && x > 0)      ? row[x - 1] : 0.f;
                win[ci][r][1] = vy                  ? row[x]     : 0.f;
                win[ci][r][2] = (vy && x < W_ - 1) ? row[x + 1] : 0.f;
            }

        float acc[TAPS];
        #pragma unroll
        for (int t = 0; t < TAPS; ++t) acc[t] = b2[t];

        for (int c = 0; c < C_; ++c) {
            const float* wc = w1 + c * 27;
            float h0 = b1[c], h1 = 0.f, h2 = 0.f;
            #pragma unroll
            for (int r = 0; r < 3; ++r)
                #pragma unroll
                for (int j = 0; j < 3; ++j) {
                    h0 = fmaf(wc[(0 * 3 + r) * 3 + j], win[0][r][j], h0);
                    h1 = fmaf(wc[(1 * 3 + r) * 3 + j], win[1][r][j], h1);
                    h2 = fmaf(wc[(2 * 3 + r) * 3 + j], win[2][r][j], h2);
                }
            const float hsum = fmaxf((h0 + h1) + h2, 0.f);
            const float4 wa = *(const float4*)&w2t[c][0];
            const float4 wb = *(const float4*)&w2t[c][4];
            const float  w8 = w2t[c][8];
            acc[0] = fmaf(wa.x, hsum, acc[0]);
            acc[1] = fmaf(wa.y, hsum, acc[1]);
            acc[2] = fmaf(wa.z, hsum, acc[2]);
            acc[3] = fmaf(wa.w, hsum, acc[3]);
            acc[4] = fmaf(wb.x, hsum, acc[4]);
            acc[5] = fmaf(wb.y, hsum, acc[5]);
            acc[6] = fmaf(wb.z, hsum, acc[6]);
            acc[7] = fmaf(wb.w, hsum, acc[7]);
            acc[8] = fmaf(w8,  hsum, acc[8]);
        }
        #pragma unroll
        for (int t = 0; t < TAPS; ++t) kernS[t][x] = acc[t];
    }
    __syncthreads();

    const int lane = tid & 63;
    const int wav  = tid >> 6;
    const int x0   = lane * 4;

    float4 kt[TAPS];
    #pragma unroll
    for (int t = 0; t < TAPS; ++t) kt[t] = *(const float4*)&kernS[t][x0];

    #pragma unroll 4
    for (int cc = 0; cc < 16; ++cc) {
        const int c = wav * 16 + cc;
        const float* hb = hin + (size_t)(b * C_ + c) * H_ * W_;

        float4 rowv[3];
        float  lft[3], rgt[3];
        #pragma unroll
        for (int r = 0; r < 3; ++r) {
            const int yy = y + r - 1;
            const bool vy = (unsigned)yy < (unsigned)H_;
            float4 m;
            if (vy) m = *(const float4*)(hb + (size_t)yy * W_ + x0);
            else    m = make_float4(0.f, 0.f, 0.f, 0.f);
            rowv[r] = m;
            float l  = __shfl_up(m.w, 1);
            float rr = __shfl_down(m.x, 1);
            if (lane == 0)  l  = 0.f;
            if (lane == 63) rr = 0.f;
            lft[r] = l; rgt[r] = rr;
        }

        float sim0 = 0.f, sim1 = 0.f, sim2 = 0.f, sim3 = 0.f;
        #pragma unroll
        for (int r = 0; r < 3; ++r) {
            const float w6_0 = lft[r];
            const float w6_1 = rowv[r].x;
            const float w6_2 = rowv[r].y;
            const float w6_3 = rowv[r].z;
            const float w6_4 = rowv[r].w;
            const float w6_5 = rgt[r];
            { const float4 k4 = kt[r*3+0];
              sim0 = fmaf(w6_0, k4.x, sim0); sim1 = fmaf(w6_1, k4.y, sim1);
              sim2 = fmaf(w6_2, k4.z, sim2); sim3 = fmaf(w6_3, k4.w, sim3); }
            { const float4 k4 = kt[r*3+1];
              sim0 = fmaf(w6_1, k4.x, sim0); sim1 = fmaf(w6_2, k4.y, sim1);
              sim2 = fmaf(w6_3, k4.z, sim2); sim3 = fmaf(w6_4, k4.w, sim3); }
            { const float4 k4 = kt[r*3+2];
              sim0 = fmaf(w6_2, k4.x, sim0); sim1 = fmaf(w6_3, k4.y, sim1);
              sim2 = fmaf(w6_4, k4.z, sim2); sim3 = fmaf(w6_5, k4.w, sim3); }
        }

        float4 o;
        o.x = rowv[1].x * __builtin_amdgcn_rcpf(1.f + __expf(-sim0));
        o.y = rowv[1].y * __builtin_amdgcn_rcpf(1.f + __expf(-sim1));
        o.z = rowv[1].z * __builtin_amdgcn_rcpf(1.f + __expf(-sim2));
        o.w = rowv[1].w * __builtin_amdgcn_rcpf(1.f + __expf(-sim3));
        *(float4*)(out + ((size_t)(b * C_ + c) * H_ + y) * W_ + x0) = o;
    }
}

extern "C" void kernel_launch(void* const* d_in, const int* in_sizes, int n_in,
                              void* d_out, int out_size, void* d_ws, size_t ws_size,
                              hipStream_t stream) {
    const float* lr  = (const float*)d_in[0];  // [8,3,256,256]
    const float* hin = (const float*)d_in[1];  // [8,64,256,256]
    const float* w1  = (const float*)d_in[2];  // [64,3,3,3]
    const float* b1  = (const float*)d_in[3];  // [64]
    const float* w2  = (const float*)d_in[4];  // [9,64,1,1]
    const float* b2  = (const float*)d_in[5];  // [9]
    float* out = (float*)d_out;                // [8,64,256,256]

    const size_t kern_bytes = (size_t)B_ * H_ * TAPS * W_ * sizeof(float);

    if (ws_size >= kern_bytes) {
        float* kws = (float*)d_ws;
        hipLaunchKernelGGL(hsa_kern, dim3(B_ * H_), dim3(256), 0, stream,
                           lr, w1, b1, w2, b2, kws);
        hipLaunchKernelGGL(hsa_gate, dim3(B_ * H_ * 8), dim3(256), 0, stream,
                           hin, kws, out);   // 16384 blocks
    } else {
        hipLaunchKernelGGL(hsa_fused, dim3(B_ * H_), dim3(256), 0, stream,
                           lr, hin, w1, b1, w2, b2, out);
    }
}

// Round 7
// 107.494 us; speedup vs baseline: 1.4279x; 1.4279x over previous
//
#include <hip/hip_runtime.h>
#include <hip/hip_bf16.h>
#include <math.h>

// Problem constants (from reference setup_inputs)
constexpr int B_  = 8;
constexpr int CIN = 3;
constexpr int C_  = 64;
constexpr int H_  = 256;
constexpr int W_  = 256;
constexpr int TAPS = 9;   // K*K, K=3

typedef float f32x4 __attribute__((ext_vector_type(4)));

// ============================================================================
// Kernel 1 (compute-bound): kern[b][y][t][x] = conv1x1(relu(conv3x3(lr)))
// One block per (b,y) row, thread = x pixel. ~2.4K FMA/thread, tiny memory.
// ============================================================================
__global__ __launch_bounds__(256, 4)
void hsa_kern(const float* __restrict__ lr,
              const float* __restrict__ w1,
              const float* __restrict__ b1,
              const float* __restrict__ w2,
              const float* __restrict__ b2,
              float* __restrict__ kws)
{
    __shared__ float w2t[C_][12];       // transposed 1x1 weights

    const int tid = threadIdx.x;
    const int blk = blockIdx.x;         // 0 .. B_*H_-1
    const int b = blk / H_;
    const int y = blk % H_;

    for (int i = tid; i < TAPS * C_; i += 256) {
        const int t = i / C_;
        const int c = i % C_;
        w2t[c][t] = w2[i];
    }
    __syncthreads();

    const int x = tid;                  // 0..255
    float win[CIN][3][3];
    #pragma unroll
    for (int ci = 0; ci < CIN; ++ci) {
        #pragma unroll
        for (int r = 0; r < 3; ++r) {
            const int yy = y + r - 1;
            const bool vy = (unsigned)yy < (unsigned)H_;
            const float* row = lr + ((size_t)(b * CIN + ci) * H_ + yy) * W_;
            win[ci][r][0] = (vy && x > 0)       ? row[x - 1] : 0.f;
            win[ci][r][1] = vy                   ? row[x]     : 0.f;
            win[ci][r][2] = (vy && x < W_ - 1)  ? row[x + 1] : 0.f;
        }
    }

    float acc[TAPS];
    #pragma unroll
    for (int t = 0; t < TAPS; ++t) acc[t] = b2[t];

    for (int c = 0; c < C_; ++c) {
        // conv1 (3x3, cin=3): three 9-deep chains (wave-uniform weights)
        const float* wc = w1 + c * 27;
        float h0 = b1[c], h1 = 0.f, h2 = 0.f;
        #pragma unroll
        for (int r = 0; r < 3; ++r)
            #pragma unroll
            for (int j = 0; j < 3; ++j) {
                h0 = fmaf(wc[(0 * 3 + r) * 3 + j], win[0][r][j], h0);
                h1 = fmaf(wc[(1 * 3 + r) * 3 + j], win[1][r][j], h1);
                h2 = fmaf(wc[(2 * 3 + r) * 3 + j], win[2][r][j], h2);
            }
        const float hsum = fmaxf((h0 + h1) + h2, 0.f);   // ReLU

        const float4 wa = *(const float4*)&w2t[c][0];
        const float4 wb = *(const float4*)&w2t[c][4];
        const float  w8 = w2t[c][8];
        acc[0] = fmaf(wa.x, hsum, acc[0]);
        acc[1] = fmaf(wa.y, hsum, acc[1]);
        acc[2] = fmaf(wa.z, hsum, acc[2]);
        acc[3] = fmaf(wa.w, hsum, acc[3]);
        acc[4] = fmaf(wb.x, hsum, acc[4]);
        acc[5] = fmaf(wb.y, hsum, acc[5]);
        acc[6] = fmaf(wb.z, hsum, acc[6]);
        acc[7] = fmaf(wb.w, hsum, acc[7]);
        acc[8] = fmaf(w8,  hsum, acc[8]);
    }

    // kws layout [b][y][t][x] -> 9 coalesced 1KB stores
    float* kr = kws + (size_t)(b * H_ + y) * TAPS * W_;
    #pragma unroll
    for (int t = 0; t < TAPS; ++t) kr[t * W_ + x] = acc[t];
}

// ============================================================================
// Kernel 2 (memory-bound): out = h * sigmoid(sum_taps shifted(h) * kern)
// Block = (b,y) row (XCD-swizzled), wave w owns channels [16w,16w+16).
// Channel loop is an EXPLICIT 2-buffer software pipeline with named registers
// and UNCONDITIONAL loads (y-halo via clamped offset + mask multiply), so ~6
// float4 loads per wave stay in flight under every compute phase. R4-R6 all
// sat at VALUBusy~17% because the compiler kept only one iteration's loads
// outstanding (VGPR_Count 32-40).
// ============================================================================
__global__ __launch_bounds__(256, 4)
void hsa_gate(const float* __restrict__ hin,
              const float* __restrict__ kws,
              float* __restrict__ out)
{
    __shared__ float kernS[TAPS][W_];   // 9 KB

    const int tid = threadIdx.x;
    const int bid = blockIdx.x;
    // bijective XCD swizzle: 2048 blocks = 8 XCDs x 256
    const int nb  = (bid & 7) * (B_ * H_ / 8) + (bid >> 3);
    const int b = nb / H_;
    const int y = nb % H_;

    const int lane = tid & 63;
    const int wav  = tid >> 6;
    const int x0   = lane * 4;
    const int cbase = wav * 16;

    const int ym1 = (y > 0) ? (y - 1) : 0;           // clamped (masked later)
    const int yp1 = (y < H_ - 1) ? (y + 1) : (H_ - 1);
    const float mask0 = (y > 0) ? 1.f : 0.f;
    const float mask2 = (y < H_ - 1) ? 1.f : 0.f;

    const float* hb = hin + (size_t)b * C_ * H_ * W_;
    const size_t plane  = (size_t)H_ * W_;
    const size_t off_m1 = (size_t)ym1 * W_ + x0;
    const size_t off_c  = (size_t)y   * W_ + x0;
    const size_t off_p1 = (size_t)yp1 * W_ + x0;

    float4 A0, A1, A2, A3, A4, A5;      // pair buffer A: 2 channels x 3 rows
    float4 B0, B1, B2, B3, B4, B5;      // pair buffer B

#define LOADP(R0, R1, R2, R3, R4, R5, pp) do {                      \
        const float* q0 = hb + (size_t)(cbase + 2 * (pp)) * plane;  \
        const float* q1 = q0 + plane;                               \
        R0 = *(const float4*)(q0 + off_m1);                         \
        R1 = *(const float4*)(q0 + off_c );                         \
        R2 = *(const float4*)(q0 + off_p1);                         \
        R3 = *(const float4*)(q1 + off_m1);                         \
        R4 = *(const float4*)(q1 + off_c );                         \
        R5 = *(const float4*)(q1 + off_p1);                         \
    } while (0)

    // issue first two pair-loads BEFORE kern staging: latency overlaps it
    LOADP(A0, A1, A2, A3, A4, A5, 0);
    LOADP(B0, B1, B2, B3, B4, B5, 1);

    // stage kern row (contiguous 9 KB)
    const float* kr = kws + (size_t)(b * H_ + y) * TAPS * W_;
    for (int i = tid; i < TAPS * W_; i += 256)
        ((float*)kernS)[i] = kr[i];
    __syncthreads();

    float4 kt[TAPS];
    #pragma unroll
    for (int t = 0; t < TAPS; ++t) kt[t] = *(const float4*)&kernS[t][x0];

    auto gate_ch = [&](float4 r0, float4 r1, float4 r2, int c) {
        r0.x *= mask0; r0.y *= mask0; r0.z *= mask0; r0.w *= mask0;
        r2.x *= mask2; r2.y *= mask2; r2.z *= mask2; r2.w *= mask2;
        const float4 rows[3] = { r0, r1, r2 };
        float sim0 = 0.f, sim1 = 0.f, sim2 = 0.f, sim3 = 0.f;
        #pragma unroll
        for (int r = 0; r < 3; ++r) {
            const float4 mv = rows[r];
            float l  = __shfl_up(mv.w, 1);     // column halo via shuffle
            float rr = __shfl_down(mv.x, 1);
            if (lane == 0)  l  = 0.f;          // x = -1 zero pad
            if (lane == 63) rr = 0.f;          // x = 256 zero pad
            const float4 k0 = kt[r * 3 + 0];
            const float4 k1 = kt[r * 3 + 1];
            const float4 k2 = kt[r * 3 + 2];
            sim0 = fmaf(l,    k0.x, sim0); sim1 = fmaf(mv.x, k0.y, sim1);
            sim2 = fmaf(mv.y, k0.z, sim2); sim3 = fmaf(mv.z, k0.w, sim3);
            sim0 = fmaf(mv.x, k1.x, sim0); sim1 = fmaf(mv.y, k1.y, sim1);
            sim2 = fmaf(mv.z, k1.z, sim2); sim3 = fmaf(mv.w, k1.w, sim3);
            sim0 = fmaf(mv.y, k2.x, sim0); sim1 = fmaf(mv.z, k2.y, sim1);
            sim2 = fmaf(mv.w, k2.z, sim2); sim3 = fmaf(rr,   k2.w, sim3);
        }
        float4 o;
        o.x = r1.x * __builtin_amdgcn_rcpf(1.f + __expf(-sim0));
        o.y = r1.y * __builtin_amdgcn_rcpf(1.f + __expf(-sim1));
        o.z = r1.z * __builtin_amdgcn_rcpf(1.f + __expf(-sim2));
        o.w = r1.w * __builtin_amdgcn_rcpf(1.f + __expf(-sim3));
        *(float4*)(out + ((size_t)(b * C_ + c) * H_ + y) * W_ + x0) = o;
    };

    // 8 channel-pairs, 2-buffer pipeline: while computing one buffer, the
    // other buffer's 6 loads are in flight.
    #pragma unroll
    for (int pp = 0; pp < 8; pp += 2) {
        gate_ch(A0, A1, A2, cbase + 2 * pp);
        gate_ch(A3, A4, A5, cbase + 2 * pp + 1);
        if (pp + 2 < 8) LOADP(A0, A1, A2, A3, A4, A5, pp + 2);
        gate_ch(B0, B1, B2, cbase + 2 * pp + 2);
        gate_ch(B3, B4, B5, cbase + 2 * pp + 3);
        if (pp + 3 < 8) LOADP(B0, B1, B2, B3, B4, B5, pp + 3);
    }
#undef LOADP
}

// ============================================================================
// Fallback: single fused kernel (used only if ws_size is too small)
// ============================================================================
__global__ __launch_bounds__(256, 4)
void hsa_fused(const float* __restrict__ lr,
               const float* __restrict__ hin,
               const float* __restrict__ w1,
               const float* __restrict__ b1,
               const float* __restrict__ w2,
               const float* __restrict__ b2,
               float* __restrict__ out)
{
    __shared__ float kernS[TAPS][W_];
    __shared__ float w2t[C_][12];

    const int tid = threadIdx.x;
    const int blk = blockIdx.x;
    const int b = blk / H_;
    const int y = blk % H_;

    for (int i = tid; i < TAPS * C_; i += 256) {
        const int t = i / C_;
        const int c = i % C_;
        w2t[c][t] = w2[i];
    }
    __syncthreads();

    {
        const int x = tid;
        float win[CIN][3][3];
        #pragma unroll
        for (int ci = 0; ci < CIN; ++ci)
            #pragma unroll
            for (int r = 0; r < 3; ++r) {
                const int yy = y + r - 1;
                const bool vy = (unsigned)yy < (unsigned)H_;
                const float* row = lr + ((size_t)(b * CIN + ci) * H_ + yy) * W_;
                win[ci][r][0] = (vy && x > 0)      ? row[x - 1] : 0.f;
                win[ci][r][1] = vy                  ? row[x]     : 0.f;
                win[ci][r][2] = (vy && x < W_ - 1) ? row[x + 1] : 0.f;
            }

        float acc[TAPS];
        #pragma unroll
        for (int t = 0; t < TAPS; ++t) acc[t] = b2[t];

        for (int c = 0; c < C_; ++c) {
            const float* wc = w1 + c * 27;
            float h0 = b1[c], h1 = 0.f, h2 = 0.f;
            #pragma unroll
            for (int r = 0; r < 3; ++r)
                #pragma unroll
                for (int j = 0; j < 3; ++j) {
                    h0 = fmaf(wc[(0 * 3 + r) * 3 + j], win[0][r][j], h0);
                    h1 = fmaf(wc[(1 * 3 + r) * 3 + j], win[1][r][j], h1);
                    h2 = fmaf(wc[(2 * 3 + r) * 3 + j], win[2][r][j], h2);
                }
            const float hsum = fmaxf((h0 + h1) + h2, 0.f);
            const float4 wa = *(const float4*)&w2t[c][0];
            const float4 wb = *(const float4*)&w2t[c][4];
            const float  w8 = w2t[c][8];
            acc[0] = fmaf(wa.x, hsum, acc[0]);
            acc[1] = fmaf(wa.y, hsum, acc[1]);
            acc[2] = fmaf(wa.z, hsum, acc[2]);
            acc[3] = fmaf(wa.w, hsum, acc[3]);
            acc[4] = fmaf(wb.x, hsum, acc[4]);
            acc[5] = fmaf(wb.y, hsum, acc[5]);
            acc[6] = fmaf(wb.z, hsum, acc[6]);
            acc[7] = fmaf(wb.w, hsum, acc[7]);
            acc[8] = fmaf(w8,  hsum, acc[8]);
        }
        #pragma unroll
        for (int t = 0; t < TAPS; ++t) kernS[t][x] = acc[t];
    }
    __syncthreads();

    const int lane = tid & 63;
    const int wav  = tid >> 6;
    const int x0   = lane * 4;

    float4 kt[TAPS];
    #pragma unroll
    for (int t = 0; t < TAPS; ++t) kt[t] = *(const float4*)&kernS[t][x0];

    #pragma unroll 4
    for (int cc = 0; cc < 16; ++cc) {
        const int c = wav * 16 + cc;
        const float* hb = hin + (size_t)(b * C_ + c) * H_ * W_;

        float4 rowv[3];
        float  lft[3], rgt[3];
        #pragma unroll
        for (int r = 0; r < 3; ++r) {
            const int yy = y + r - 1;
            const bool vy = (unsigned)yy < (unsigned)H_;
            float4 m;
            if (vy) m = *(const float4*)(hb + (size_t)yy * W_ + x0);
            else    m = make_float4(0.f, 0.f, 0.f, 0.f);
            rowv[r] = m;
            float l  = __shfl_up(m.w, 1);
            float rr = __shfl_down(m.x, 1);
            if (lane == 0)  l  = 0.f;
            if (lane == 63) rr = 0.f;
            lft[r] = l; rgt[r] = rr;
        }

        float sim0 = 0.f, sim1 = 0.f, sim2 = 0.f, sim3 = 0.f;
        #pragma unroll
        for (int r = 0; r < 3; ++r) {
            const float w6_0 = lft[r];
            const float w6_1 = rowv[r].x;
            const float w6_2 = rowv[r].y;
            const float w6_3 = rowv[r].z;
            const float w6_4 = rowv[r].w;
            const float w6_5 = rgt[r];
            { const float4 k4 = kt[r*3+0];
              sim0 = fmaf(w6_0, k4.x, sim0); sim1 = fmaf(w6_1, k4.y, sim1);
              sim2 = fmaf(w6_2, k4.z, sim2); sim3 = fmaf(w6_3, k4.w, sim3); }
            { const float4 k4 = kt[r*3+1];
              sim0 = fmaf(w6_1, k4.x, sim0); sim1 = fmaf(w6_2, k4.y, sim1);
              sim2 = fmaf(w6_3, k4.z, sim2); sim3 = fmaf(w6_4, k4.w, sim3); }
            { const float4 k4 = kt[r*3+2];
              sim0 = fmaf(w6_2, k4.x, sim0); sim1 = fmaf(w6_3, k4.y, sim1);
              sim2 = fmaf(w6_4, k4.z, sim2); sim3 = fmaf(w6_5, k4.w, sim3); }
        }

        float4 o;
        o.x = rowv[1].x * __builtin_amdgcn_rcpf(1.f + __expf(-sim0));
        o.y = rowv[1].y * __builtin_amdgcn_rcpf(1.f + __expf(-sim1));
        o.z = rowv[1].z * __builtin_amdgcn_rcpf(1.f + __expf(-sim2));
        o.w = rowv[1].w * __builtin_amdgcn_rcpf(1.f + __expf(-sim3));
        *(float4*)(out + ((size_t)(b * C_ + c) * H_ + y) * W_ + x0) = o;
    }
}

extern "C" void kernel_launch(void* const* d_in, const int* in_sizes, int n_in,
                              void* d_out, int out_size, void* d_ws, size_t ws_size,
                              hipStream_t stream) {
    const float* lr  = (const float*)d_in[0];  // [8,3,256,256]
    const float* hin = (const float*)d_in[1];  // [8,64,256,256]
    const float* w1  = (const float*)d_in[2];  // [64,3,3,3]
    const float* b1  = (const float*)d_in[3];  // [64]
    const float* w2  = (const float*)d_in[4];  // [9,64,1,1]
    const float* b2  = (const float*)d_in[5];  // [9]
    float* out = (float*)d_out;                // [8,64,256,256]

    const size_t kern_bytes = (size_t)B_ * H_ * TAPS * W_ * sizeof(float);

    if (ws_size >= kern_bytes) {
        float* kws = (float*)d_ws;
        hipLaunchKernelGGL(hsa_kern, dim3(B_ * H_), dim3(256), 0, stream,
                           lr, w1, b1, w2, b2, kws);
        hipLaunchKernelGGL(hsa_gate, dim3(B_ * H_), dim3(256), 0, stream,
                           hin, kws, out);
    } else {
        hipLaunchKernelGGL(hsa_fused, dim3(B_ * H_), dim3(256), 0, stream,
                           lr, hin, w1, b1, w2, b2, out);
    }
}